// Round 1
// baseline (104.032 us; speedup 1.0000x reference)
//
#include <hip/hip_runtime.h>

// Problem constants (from reference: B=8, N=8192, M=2500, P=10)
#define B_   8
#define N_   8192
#define M_   2500
#define SPP_ 250
#define EPS_ 1e-20f
#define BIGF 1e30f

// ---- kernel-1 roles ----
// unified chamfer: 8 gtblk (1024 gt) x 8 b x 5 mblk (512 preds) = 320 blocks.
// Each block computes its 512x1024 distance tile ONCE and extracts BOTH
// row-minima (p2gt partial, over this gt chunk) and col-minima (gt2p
// partial, over this pred chunk). Halves MFMA count vs two-role version.
#define NB_CH   320
#define NB_FFF  79
#define NB_K1   (NB_CH + NB_FFF)   // 399 blocks -> <=2 blocks/CU, one pass

// ---- kernel-2 roles ----
#define NB_RG2P 256
#define NB_RP2  79
#define NB_K2   (NB_RG2P + NB_RP2)             // 335

// ---- ws layout (float indices) ----
#define WS_P2GT 0            // [8 z][8 b][2500] clamped partial row minima
#define WS_GT2P 160000       // [5 mblk][8 b][8192] clamped partial col minima
#define WS_ACC  487680       // 20 float accumulators (atomicAdd targets, k1)
#define WS_RED  487700       // k2 partials: 256 g2p + 79 p2
#define WS_CNT  488035       // k2 arrival counter (uint)
// acc slots
#define A_E    0
#define A_G    1
#define A_MC   2
#define A_ST   3
#define A_F2I  4
#define A_E2I  5
#define A_EI   6
#define A_G2I  7
#define A_GI   8
#define A_I    9
#define A_AB   10   // 10..17 per-batch sum sqrt(A2)
#define RO_G2P 0
#define RO_P2  256

typedef __attribute__((ext_vector_type(8))) short short8_t;
typedef __attribute__((ext_vector_type(4))) float float4_t;

__device__ __forceinline__ unsigned pack_bf2(float lo, float hi) {
    unsigned a = __float_as_uint(lo);
    unsigned b = __float_as_uint(hi);
    a = (a + 0x7FFFu + ((a >> 16) & 1u)) >> 16;
    b = (b + 0x7FFFu + ((b >> 16) & 1u)) & 0xFFFF0000u;
    return a | b;
}
__device__ __forceinline__ short bf16s(float x) {
    unsigned a = __float_as_uint(x);
    return (short)((a + 0x7FFFu + ((a >> 16) & 1u)) >> 16);
}
__device__ __forceinline__ float wave_sum64(float v) {
    #pragma unroll
    for (int o = 32; o > 0; o >>= 1) v += __shfl_down(v, o, 64);
    return v;
}
__device__ __forceinline__ float block_sum256(float v, volatile float* red4) {
    v = wave_sum64(v);
    int wid = threadIdx.x >> 6, lane = threadIdx.x & 63;
    if (lane == 0) red4[wid] = v;
    __syncthreads();
    float r = 0.f;
    if (threadIdx.x == 0) r = red4[0] + red4[1] + red4[2] + red4[3];
    __syncthreads();
    return r;
}
__device__ __forceinline__ void min4(float4_t& c, const float4_t d) {
    c.x = fminf(c.x, d.x); c.y = fminf(c.y, d.y);
    c.z = fminf(c.z, d.z); c.w = fminf(c.w, d.w);
}
__device__ __forceinline__ void quad_min4(float4_t& c) {
    #pragma unroll
    for (int m = 1; m < 16; m <<= 1) {
        c.x = fminf(c.x, __shfl_xor(c.x, m, 64));
        c.y = fminf(c.y, __shfl_xor(c.y, m, 64));
        c.z = fminf(c.z, __shfl_xor(c.z, m, 64));
        c.w = fminf(c.w, __shfl_xor(c.w, m, 64));
    }
}

// ============================================================================
// Kernel 1: MFMA chamfer (ONE distance-matrix pass, both reductions) + fff.
// Per 512x1024 tile: row-min path identical to previous version (p2gt
// numerics unchanged); col-min extracted per 16-col tile via reg collapse +
// cross-quad shfl into per-wave LDS arrays (no cross-wave races), combined
// in the epilogue. __launch_bounds__(256, 2): keep <=256 VGPR, 2 blocks/CU.
// ============================================================================
__global__ void __launch_bounds__(256, 2) k1_main(
        const float* __restrict__ gt, const float* __restrict__ pred,
        const float* __restrict__ fff, float* __restrict__ ws) {
    __shared__ uint4 spts[1024];                 // staged gt pts, 16 B each
    __shared__ __align__(16) float saux[516];    // 512 row norms + red4
    __shared__ float scol[4][1024];              // per-wave col minima
    const int bid = blockIdx.x;
    const int tid = threadIdx.x;
    const int lane = tid & 63;
    const int w    = tid >> 6;
    const int quad = lane >> 4;
    const int l15  = lane & 15;
    float* acc = ws + WS_ACC;

    if (bid == 0 && tid == 0) ((unsigned*)(ws + WS_CNT))[0] = 0u;

    if (bid < NB_CH) {
        // ------------------- unified chamfer role -------------------
        const int z = bid / 40;         // gt chunk (1024 pts)
        const int rem = bid % 40;
        const int b = rem / 5;
        const int mblk = rem % 5;       // pred chunk (512 rows)
        const float* apts = pred + (size_t)b * M_ * 3;
        const float* bpts = gt + ((size_t)b * N_ + (size_t)z * 1024) * 3;
        const int alim = M_;
        const int abase = mblk * 512;
        float* dstR = ws + WS_P2GT + (size_t)z * 20000 + b * M_;
        float* dstC = ws + WS_GT2P + (size_t)mblk * 65536 + b * N_ + z * 1024;

        // stage gt points (bf16, -2 folded, norm in w; halves duplicated)
        for (int i = tid; i < 1024; i += 256) {
            const float* q3 = bpts + i * 3;
            float x = q3[0], y = q3[1], zc = q3[2];
            float n2 = x * x + y * y + zc * zc;
            uint4 q;
            q.x = pack_bf2(-2.f * x, -2.f * y);
            q.y = pack_bf2(-2.f * zc, n2);
            q.z = q.x; q.w = q.y;
            spts[i] = q;
        }

        // A fragments: 8 tiles of 16 rows per wave (128 rows); stash norms
        short8_t af[8];
        #pragma unroll
        for (int t = 0; t < 8; ++t) af[t] = (short8_t){0,0,0,0,0,0,0,0};
        if (lane < 16) {
            #pragma unroll
            for (int t = 0; t < 8; ++t) {
                int m = abase + w * 128 + t * 16 + l15;
                int c = m < alim ? m : alim - 1;   // dup row 2499 (harmless both dirs)
                float x = apts[c*3+0], y = apts[c*3+1], zc = apts[c*3+2];
                af[t][0] = bf16s(x); af[t][1] = bf16s(y); af[t][2] = bf16s(zc);
                af[t][3] = (short)0x3F80;  // 1.0 bf16
                saux[w * 128 + t * 16 + l15] = x*x + y*y + zc*zc;
            }
        }
        __syncthreads();

        const float4_t* bp = (const float4_t*)saux;
        float4_t bias[8], c[8];
        #pragma unroll
        for (int t = 0; t < 8; ++t) {
            bias[t] = bp[w * 32 + t * 4 + quad];
            c[t] = (float4_t){BIGF, BIGF, BIGF, BIGF};
        }

        const uint4* bptr = spts + l15;   // quads duplicate address = broadcast
        #pragma unroll 2
        for (int i = 0; i < 64; ++i) {
            short8_t bf = __builtin_bit_cast(short8_t, bptr[i * 16]);
            float cmA = BIGF, cmB = BIGF;   // two chains for ILP
            #pragma unroll
            for (int t = 0; t < 8; ++t) {
                float4_t d = __builtin_amdgcn_mfma_f32_16x16x32_bf16(
                                 af[t], bf, bias[t], 0, 0, 0);
                min4(c[t], d);                              // row accumulate
                float m0 = fminf(fminf(d.x, d.y), fminf(d.z, d.w));
                if (t & 1) cmB = fminf(cmB, m0); else cmA = fminf(cmA, m0);
            }
            float cm = fminf(cmA, cmB);
            cm = fminf(cm, __shfl_xor(cm, 16, 64));         // across quads
            cm = fminf(cm, __shfl_xor(cm, 32, 64));
            if (lane < 16) scol[w][i * 16 + l15] = cm;      // per-wave, no race
        }

        // ---- row (p2gt) epilogue: unchanged ----
        #pragma unroll
        for (int t = 0; t < 8; ++t) {
            quad_min4(c[t]);
            c[t].x = fmaxf(c[t].x, 0.f); c[t].y = fmaxf(c[t].y, 0.f);
            c[t].z = fmaxf(c[t].z, 0.f); c[t].w = fmaxf(c[t].w, 0.f);
        }
        if (l15 == 0) {
            #pragma unroll
            for (int t = 0; t < 8; ++t) {
                int m0 = abase + w * 128 + t * 16 + quad * 4;
                if (m0 < alim)   // alim % 4 == 0 -> no straddle
                    *(float4_t*)(dstR + m0) = c[t];
            }
        }

        // ---- col (gt2p) epilogue: combine the 4 waves ----
        __syncthreads();
        #pragma unroll
        for (int j = tid; j < 1024; j += 256) {
            float v = fminf(fminf(scol[0][j], scol[1][j]),
                            fminf(scol[2][j], scol[3][j]));
            dstC[j] = fmaxf(v, 0.f);
        }
    } else {
        // ------------- fff role (single pass, expanded variance) -------------
        const int kb = bid - NB_CH;
        const int i  = kb * 256 + tid;
        volatile float* red4 = saux + 512;
        float* sA = saux;   // [0..7]
        if (tid < B_) sA[tid] = 0.f;
        __syncthreads();

        float vE=0.f,vG=0.f,vMC=0.f,vST=0.f,vF2=0.f,vE2=0.f,vEI=0.f,
              vG2=0.f,vGI=0.f,vI=0.f;
        if (i < B_ * M_) {
            const int b = i / M_;
            const int m = i - b * M_;
            const float* f = fff + (size_t)i * 3;
            float E = f[0], F = f[1], G = f[2];
            float A2  = fmaxf(E * G - F * F, 0.f);
            float inv = 1.f / (A2 + EPS_);
            vE = E; vG = G;
            vST = (E - G) * (E - G) * inv;
            vF2 = F * F * inv;
            vE2 = E * E * inv; vEI = E * inv;
            vG2 = G * G * inv; vGI = G * inv;
            vI  = inv;
            atomicAdd(&sA[b], sqrtf(A2));
            if ((b & 1) == 0) {
                const float* f2 = fff + ((size_t)(b + 1) * M_ + m) * 3;
                float dE = E - f2[0], dF = F - f2[1], dG = G - f2[2];
                vMC = dE * dE + 2.f * dF * dF + dG * dG;
            }
        }
        float r;
        r = block_sum256(vE,  red4); if (tid==0) atomicAdd(&acc[A_E],   r);
        r = block_sum256(vG,  red4); if (tid==0) atomicAdd(&acc[A_G],   r);
        r = block_sum256(vMC, red4); if (tid==0) atomicAdd(&acc[A_MC],  r);
        r = block_sum256(vST, red4); if (tid==0) atomicAdd(&acc[A_ST],  r);
        r = block_sum256(vF2, red4); if (tid==0) atomicAdd(&acc[A_F2I], r);
        r = block_sum256(vE2, red4); if (tid==0) atomicAdd(&acc[A_E2I], r);
        r = block_sum256(vEI, red4); if (tid==0) atomicAdd(&acc[A_EI],  r);
        r = block_sum256(vG2, red4); if (tid==0) atomicAdd(&acc[A_G2I], r);
        r = block_sum256(vGI, red4); if (tid==0) atomicAdd(&acc[A_GI],  r);
        r = block_sum256(vI,  red4); if (tid==0) atomicAdd(&acc[A_I],   r);
        __syncthreads();
        if (tid < B_ && sA[tid] != 0.f) atomicAdd(&acc[A_AB + tid], sA[tid]);
    }
}

// ============================================================================
// Kernel 2: min-over-chunks both directions + last-block finalize.
// gt2p partials: now 5 (pred chunks); p2gt partials: 8 (gt chunks).
// ============================================================================
__global__ void __launch_bounds__(256) k2_reduce(
        const float* __restrict__ fff, const float* __restrict__ A_gt,
        float* __restrict__ ws, float* __restrict__ out) {
    __shared__ float red4[4];
    const int bid = blockIdx.x;
    const int tid = threadIdx.x;
    float* redp = ws + WS_RED;
    float* acc  = ws + WS_ACC;

    if (bid < NB_RG2P) {
        const int o = bid * 256 + tid;               // [0,65536)
        const float* src = ws + WS_GT2P + o;
        float m = src[0];
        #pragma unroll
        for (int zz = 1; zz < 5; ++zz) m = fminf(m, src[zz * 65536]);
        float r = block_sum256(m, red4);             // already clamped
        if (tid == 0) redp[RO_G2P + bid] = r;
    } else {
        const int kb = bid - NB_RG2P;
        const int o = kb * 256 + tid;                // [0,20224)
        float s = 0.f;
        if (o < 20000) {
            const float* src = ws + WS_P2GT + o;
            float m = src[0];
            #pragma unroll
            for (int zz = 1; zz < 8; ++zz) m = fminf(m, src[zz * 20000]);
            s = m;
        }
        float r = block_sum256(s, red4);
        if (tid == 0) redp[RO_P2 + kb] = r;
    }

    // ---- arrival counter; last block finalizes ----
    __syncthreads();
    if (tid == 0) __threadfence();
    __syncthreads();
    __shared__ unsigned old_s;
    if (tid == 0)
        old_s = __hip_atomic_fetch_add((unsigned*)(ws + WS_CNT), 1u,
                                       __ATOMIC_ACQ_REL, __HIP_MEMORY_SCOPE_AGENT);
    __syncthreads();
    if (old_s == (unsigned)(NB_K2 - 1)) {
        float v;
        v = redp[RO_G2P + tid];
        float sGT2P = block_sum256(v, red4);
        v = (tid < 79) ? redp[RO_P2 + tid] : 0.f;
        float sP2GT = block_sum256(v, red4);
        if (tid == 0) {
            float a[18];
            #pragma unroll
            for (int k = 0; k < 18; ++k)
                a[k] = __hip_atomic_load(&acc[k], __ATOMIC_RELAXED,
                                         __HIP_MEMORY_SCOPE_AGENT);
            const float inv20k = 1.f / 20000.f;
            float mE = a[A_E] * inv20k, mG = a[A_G] * inv20k;
            float L_E = (a[A_E2I] - 2.f*mE*a[A_EI] + mE*mE*a[A_I]) * inv20k;
            float L_G = (a[A_G2I] - 2.f*mG*a[A_GI] + mG*mG*a[A_I]) * inv20k;
            float L_sc = L_E + L_G + (a[A_ST] + a[A_F2I]) * inv20k;
            float L_mc = a[A_MC] * (1.f / 10000.f);
            float L_chd = sP2GT * inv20k + sGT2P * (1.f / 65536.f);
            float L_olap = 0.f;
            #pragma unroll
            for (int b = 0; b < B_; ++b) {
                float At = a[A_AB + b] * (1.f / (float)SPP_);
                float d  = fmaxf(0.f, At - A_gt[b]);
                L_olap += d * d;
            }
            L_olap *= (1.f / (float)B_);
            out[0] = L_chd + L_mc + L_sc + L_olap;
        }
    }
}

extern "C" void kernel_launch(void* const* d_in, const int* in_sizes, int n_in,
                              void* d_out, int out_size, void* d_ws, size_t ws_size,
                              hipStream_t stream) {
    const float* pc_gt   = (const float*)d_in[0];   // (8, 8192, 3)
    const float* pc_pred = (const float*)d_in[1];   // (8, 2500, 3)
    const float* fff     = (const float*)d_in[2];   // (8, 2500, 3)
    const float* A_gt    = (const float*)d_in[3];   // (8,)
    float* ws  = (float*)d_ws;                      // ~1.95 MB used
    float* out = (float*)d_out;

    // zero 20 float accumulators (80 B); k2 counter zeroed by k1 block 0
    hipMemsetAsync(ws + WS_ACC, 0, 20 * sizeof(float), stream);
    k1_main  <<<NB_K1, 256, 0, stream>>>(pc_gt, pc_pred, fff, ws);
    k2_reduce<<<NB_K2, 256, 0, stream>>>(fff, A_gt, ws, out);
}

// Round 2
// 91.466 us; speedup vs baseline: 1.1374x; 1.1374x over previous
//
#include <hip/hip_runtime.h>

// Problem constants (from reference: B=8, N=8192, M=2500, P=10)
#define B_   8
#define N_   8192
#define M_   2500
#define SPP_ 250
#define EPS_ 1e-20f
#define BIGF 1e30f

// ---- kernel-1 roles ----
// unified chamfer: 16 gtblk (512 gt) x 8 b x 5 mblk (512 preds) = 640 blocks.
// Each block computes its 512x512 distance tile ONCE; row minima (p2gt) and
// col minima (gt2p) both land in tiny global arrays via atomicMin
// (float-as-int: valid because all values are clamped >= 0).
#define NB_CH   640
#define NB_FFF  79
#define NB_K1   (NB_CH + NB_FFF)   // 719

// ---- kernel-2: pure sums of the min arrays + finalize ----
#define NB_SG   64                 // 65536 gt2p minima
#define NB_SP   20                 // 20000 p2gt minima
#define NB_K2   (NB_SG + NB_SP)    // 84

// ---- ws layout (float indices) ----
#define WS_P2M  0        // [8][2500] row minima (atomicMin, init 0x7F bytes)
#define WS_G2M  20000    // [8][8192] col minima (atomicMin, init 0x7F bytes)
#define WS_ACC  85536    // 20 accumulators (+ slot 20 = k2 arrival counter)
#define WS_CNT  (WS_ACC + 20)
// acc slots
#define A_E    0
#define A_G    1
#define A_MC   2
#define A_ST   3
#define A_F2I  4
#define A_E2I  5
#define A_EI   6
#define A_G2I  7
#define A_GI   8
#define A_I    9
#define A_AB   10   // 10..17 per-batch sum sqrt(A2)
#define A_SP   18   // sum of p2gt minima
#define A_SG   19   // sum of gt2p minima

typedef __attribute__((ext_vector_type(8))) short short8_t;
typedef __attribute__((ext_vector_type(4))) float float4_t;

__device__ __forceinline__ unsigned pack_bf2(float lo, float hi) {
    unsigned a = __float_as_uint(lo);
    unsigned b = __float_as_uint(hi);
    a = (a + 0x7FFFu + ((a >> 16) & 1u)) >> 16;
    b = (b + 0x7FFFu + ((b >> 16) & 1u)) & 0xFFFF0000u;
    return a | b;
}
__device__ __forceinline__ short bf16s(float x) {
    unsigned a = __float_as_uint(x);
    return (short)((a + 0x7FFFu + ((a >> 16) & 1u)) >> 16);
}
// 3-input min, single VALU instr (values are never NaN here)
__device__ __forceinline__ float min3f(float a, float b, float c) {
    float r;
    asm("v_min3_f32 %0, %1, %2, %3" : "=v"(r) : "v"(a), "v"(b), "v"(c));
    return r;
}
__device__ __forceinline__ float wave_sum64(float v) {
    #pragma unroll
    for (int o = 32; o > 0; o >>= 1) v += __shfl_down(v, o, 64);
    return v;
}
__device__ __forceinline__ float block_sum256(float v, volatile float* red4) {
    v = wave_sum64(v);
    int wid = threadIdx.x >> 6, lane = threadIdx.x & 63;
    if (lane == 0) red4[wid] = v;
    __syncthreads();
    float r = 0.f;
    if (threadIdx.x == 0) r = red4[0] + red4[1] + red4[2] + red4[3];
    __syncthreads();
    return r;
}
__device__ __forceinline__ void quad_min4(float4_t& c) {
    #pragma unroll
    for (int m = 1; m < 16; m <<= 1) {
        c.x = fminf(c.x, __shfl_xor(c.x, m, 64));
        c.y = fminf(c.y, __shfl_xor(c.y, m, 64));
        c.z = fminf(c.z, __shfl_xor(c.z, m, 64));
        c.w = fminf(c.w, __shfl_xor(c.w, m, 64));
    }
}

// ============================================================================
// Kernel 1: MFMA chamfer (single distance-matrix pass, both reductions) + fff.
// Inner loop processes col-iterations in PAIRS so the row-min accumulate is
// one v_min3 per 2 tiles; col collapse is min3 chains; NO cross-lane ops in
// the loop (per-(wave,quad) LDS partials, combined in epilogue).
// __launch_bounds__(256, 2): <=256 VGPR (live ~190 with d0/d1 pairing).
// ============================================================================
__global__ void __launch_bounds__(256, 2) k1_main(
        const float* __restrict__ gt, const float* __restrict__ pred,
        const float* __restrict__ fff, float* __restrict__ ws) {
    __shared__ uint4 spts[512];                  // staged gt pts, 16 B each
    __shared__ __align__(16) float saux[516];    // 512 row norms + red4
    __shared__ float scol[4][4][520];            // [wave][quad][col] partials (pad 8)
    const int bid = blockIdx.x;
    const int tid = threadIdx.x;
    const int lane = tid & 63;
    const int w    = tid >> 6;
    const int quad = lane >> 4;
    const int l15  = lane & 15;
    float* acc = ws + WS_ACC;

    if (bid < NB_CH) {
        // ------------------- unified chamfer role -------------------
        const int z = bid / 40;         // gt chunk (512 pts), 16 chunks
        const int rem = bid % 40;
        const int b = rem / 5;
        const int mblk = rem % 5;       // pred chunk (512 rows)
        const float* apts = pred + (size_t)b * M_ * 3;
        const float* bpts = gt + ((size_t)b * N_ + (size_t)z * 512) * 3;
        const int abase = mblk * 512;
        float* dstR = ws + WS_P2M + (size_t)b * M_;
        float* dstC = ws + WS_G2M + (size_t)b * N_ + z * 512;

        // stage gt points (bf16, -2 folded, norm in w; halves duplicated)
        for (int i = tid; i < 512; i += 256) {
            const float* q3 = bpts + i * 3;
            float x = q3[0], y = q3[1], zc = q3[2];
            float n2 = x * x + y * y + zc * zc;
            uint4 q;
            q.x = pack_bf2(-2.f * x, -2.f * y);
            q.y = pack_bf2(-2.f * zc, n2);
            q.z = q.x; q.w = q.y;
            spts[i] = q;
        }

        // A fragments: 8 tiles of 16 rows per wave (128 rows); stash norms
        short8_t af[8];
        #pragma unroll
        for (int t = 0; t < 8; ++t) af[t] = (short8_t){0,0,0,0,0,0,0,0};
        if (lane < 16) {
            #pragma unroll
            for (int t = 0; t < 8; ++t) {
                int m = abase + w * 128 + t * 16 + l15;
                int c = m < M_ ? m : M_ - 1;   // dup row 2499 (harmless both dirs)
                float x = apts[c*3+0], y = apts[c*3+1], zc = apts[c*3+2];
                af[t][0] = bf16s(x); af[t][1] = bf16s(y); af[t][2] = bf16s(zc);
                af[t][3] = (short)0x3F80;  // 1.0 bf16
                saux[w * 128 + t * 16 + l15] = x*x + y*y + zc*zc;
            }
        }
        __syncthreads();

        const float4_t* bp = (const float4_t*)saux;
        float4_t bias[8], c[8];
        #pragma unroll
        for (int t = 0; t < 8; ++t) {
            bias[t] = bp[w * 32 + t * 4 + quad];
            c[t] = (float4_t){BIGF, BIGF, BIGF, BIGF};
        }

        const uint4* bptr = spts + l15;   // quads duplicate address = broadcast
        #pragma unroll 2
        for (int ip = 0; ip < 16; ++ip) {             // 2 col-tiles per iter
            short8_t bf0 = __builtin_bit_cast(short8_t, bptr[(2*ip+0) * 16]);
            short8_t bf1 = __builtin_bit_cast(short8_t, bptr[(2*ip+1) * 16]);
            float4_t d0[8], d1[8];
            #pragma unroll
            for (int t = 0; t < 8; ++t)
                d0[t] = __builtin_amdgcn_mfma_f32_16x16x32_bf16(af[t], bf0, bias[t], 0, 0, 0);
            #pragma unroll
            for (int t = 0; t < 8; ++t)
                d1[t] = __builtin_amdgcn_mfma_f32_16x16x32_bf16(af[t], bf1, bias[t], 0, 0, 0);
            float cA0 = BIGF, cB0 = BIGF, cA1 = BIGF, cB1 = BIGF;
            #pragma unroll
            for (int t = 0; t < 8; ++t) {
                // row accumulate: one min3 per reg per 2 tiles
                c[t].x = min3f(c[t].x, d0[t].x, d1[t].x);
                c[t].y = min3f(c[t].y, d0[t].y, d1[t].y);
                c[t].z = min3f(c[t].z, d0[t].z, d1[t].z);
                c[t].w = min3f(c[t].w, d0[t].w, d1[t].w);
                // col collapse: per-lane min over this tile's 4 rows
                float m0 = min3f(d0[t].x, d0[t].y, d0[t].z);
                float m1 = min3f(d1[t].x, d1[t].y, d1[t].z);
                if (t & 1) { cB0 = min3f(cB0, m0, d0[t].w); cB1 = min3f(cB1, m1, d1[t].w); }
                else       { cA0 = min3f(cA0, m0, d0[t].w); cA1 = min3f(cA1, m1, d1[t].w); }
            }
            scol[w][quad][(2*ip+0)*16 + l15] = fminf(cA0, cB0);
            scol[w][quad][(2*ip+1)*16 + l15] = fminf(cA1, cB1);
        }

        // ---- row (p2gt) epilogue: reduce across cols, atomicMin per row ----
        #pragma unroll
        for (int t = 0; t < 8; ++t) {
            quad_min4(c[t]);
            if (l15 == 0) {
                int m0 = abase + w * 128 + t * 16 + quad * 4;
                if (m0 < M_) {   // M_ % 4 == 0 -> rows m0..m0+3 all valid
                    atomicMin((int*)(dstR + m0 + 0), (int)__float_as_uint(fmaxf(c[t].x, 0.f)));
                    atomicMin((int*)(dstR + m0 + 1), (int)__float_as_uint(fmaxf(c[t].y, 0.f)));
                    atomicMin((int*)(dstR + m0 + 2), (int)__float_as_uint(fmaxf(c[t].z, 0.f)));
                    atomicMin((int*)(dstR + m0 + 3), (int)__float_as_uint(fmaxf(c[t].w, 0.f)));
                }
            }
        }

        // ---- col (gt2p) epilogue: combine 16 partials, atomicMin per col ----
        __syncthreads();
        #pragma unroll
        for (int rr = 0; rr < 2; ++rr) {
            int j = rr * 256 + tid;
            float v = BIGF;
            #pragma unroll
            for (int w2 = 0; w2 < 4; ++w2)
                #pragma unroll
                for (int q = 0; q < 4; ++q)
                    v = fminf(v, scol[w2][q][j]);
            atomicMin((int*)(dstC + j), (int)__float_as_uint(fmaxf(v, 0.f)));
        }
    } else {
        // ------------- fff role (single pass, expanded variance) -------------
        const int kb = bid - NB_CH;
        const int i  = kb * 256 + tid;
        volatile float* red4 = saux + 512;
        float* sA = saux;   // [0..7]
        if (tid < B_) sA[tid] = 0.f;
        __syncthreads();

        float vE=0.f,vG=0.f,vMC=0.f,vST=0.f,vF2=0.f,vE2=0.f,vEI=0.f,
              vG2=0.f,vGI=0.f,vI=0.f;
        if (i < B_ * M_) {
            const int b = i / M_;
            const int m = i - b * M_;
            const float* f = fff + (size_t)i * 3;
            float E = f[0], F = f[1], G = f[2];
            float A2  = fmaxf(E * G - F * F, 0.f);
            float inv = 1.f / (A2 + EPS_);
            vE = E; vG = G;
            vST = (E - G) * (E - G) * inv;
            vF2 = F * F * inv;
            vE2 = E * E * inv; vEI = E * inv;
            vG2 = G * G * inv; vGI = G * inv;
            vI  = inv;
            atomicAdd(&sA[b], sqrtf(A2));
            if ((b & 1) == 0) {
                const float* f2 = fff + ((size_t)(b + 1) * M_ + m) * 3;
                float dE = E - f2[0], dF = F - f2[1], dG = G - f2[2];
                vMC = dE * dE + 2.f * dF * dF + dG * dG;
            }
        }
        float r;
        r = block_sum256(vE,  red4); if (tid==0) atomicAdd(&acc[A_E],   r);
        r = block_sum256(vG,  red4); if (tid==0) atomicAdd(&acc[A_G],   r);
        r = block_sum256(vMC, red4); if (tid==0) atomicAdd(&acc[A_MC],  r);
        r = block_sum256(vST, red4); if (tid==0) atomicAdd(&acc[A_ST],  r);
        r = block_sum256(vF2, red4); if (tid==0) atomicAdd(&acc[A_F2I], r);
        r = block_sum256(vE2, red4); if (tid==0) atomicAdd(&acc[A_E2I], r);
        r = block_sum256(vEI, red4); if (tid==0) atomicAdd(&acc[A_EI],  r);
        r = block_sum256(vG2, red4); if (tid==0) atomicAdd(&acc[A_G2I], r);
        r = block_sum256(vGI, red4); if (tid==0) atomicAdd(&acc[A_GI],  r);
        r = block_sum256(vI,  red4); if (tid==0) atomicAdd(&acc[A_I],   r);
        __syncthreads();
        if (tid < B_ && sA[tid] != 0.f) atomicAdd(&acc[A_AB + tid], sA[tid]);
    }
}

// ============================================================================
// Kernel 2: sum the two min arrays (84 blocks, 336 KB total) + finalize.
// ============================================================================
__global__ void __launch_bounds__(256) k2_reduce(
        const float* __restrict__ fff, const float* __restrict__ A_gt,
        float* __restrict__ ws, float* __restrict__ out) {
    __shared__ float red4[4];
    const int bid = blockIdx.x;
    const int tid = threadIdx.x;
    float* acc = ws + WS_ACC;

    if (bid < NB_SG) {
        const float* src = ws + WS_G2M + (size_t)bid * 1024;
        float s = 0.f;
        #pragma unroll
        for (int j = 0; j < 4; ++j) s += src[tid + j * 256];
        float r = block_sum256(s, red4);
        if (tid == 0) atomicAdd(&acc[A_SG], r);
    } else {
        const int kb = bid - NB_SG;
        float s = 0.f;
        #pragma unroll
        for (int j = 0; j < 4; ++j) {
            int o = kb * 1024 + tid + j * 256;
            if (o < 20000) s += ws[WS_P2M + o];
        }
        float r = block_sum256(s, red4);
        if (tid == 0) atomicAdd(&acc[A_SP], r);
    }

    // ---- arrival counter; last block finalizes ----
    __syncthreads();
    if (tid == 0) __threadfence();
    __syncthreads();
    __shared__ unsigned old_s;
    if (tid == 0)
        old_s = __hip_atomic_fetch_add((unsigned*)(ws + WS_CNT), 1u,
                                       __ATOMIC_ACQ_REL, __HIP_MEMORY_SCOPE_AGENT);
    __syncthreads();
    if (old_s == (unsigned)(NB_K2 - 1) && tid == 0) {
        float a[20];
        #pragma unroll
        for (int k = 0; k < 20; ++k)
            a[k] = __hip_atomic_load(&acc[k], __ATOMIC_RELAXED,
                                     __HIP_MEMORY_SCOPE_AGENT);
        const float inv20k = 1.f / 20000.f;
        float mE = a[A_E] * inv20k, mG = a[A_G] * inv20k;
        float L_E = (a[A_E2I] - 2.f*mE*a[A_EI] + mE*mE*a[A_I]) * inv20k;
        float L_G = (a[A_G2I] - 2.f*mG*a[A_GI] + mG*mG*a[A_I]) * inv20k;
        float L_sc = L_E + L_G + (a[A_ST] + a[A_F2I]) * inv20k;
        float L_mc = a[A_MC] * (1.f / 10000.f);
        float L_chd = a[A_SP] * inv20k + a[A_SG] * (1.f / 65536.f);
        float L_olap = 0.f;
        #pragma unroll
        for (int b = 0; b < B_; ++b) {
            float At = a[A_AB + b] * (1.f / (float)SPP_);
            float d  = fmaxf(0.f, At - A_gt[b]);
            L_olap += d * d;
        }
        L_olap *= (1.f / (float)B_);
        out[0] = L_chd + L_mc + L_sc + L_olap;
    }
}

extern "C" void kernel_launch(void* const* d_in, const int* in_sizes, int n_in,
                              void* d_out, int out_size, void* d_ws, size_t ws_size,
                              hipStream_t stream) {
    const float* pc_gt   = (const float*)d_in[0];   // (8, 8192, 3)
    const float* pc_pred = (const float*)d_in[1];   // (8, 2500, 3)
    const float* fff     = (const float*)d_in[2];   // (8, 2500, 3)
    const float* A_gt    = (const float*)d_in[3];   // (8,)
    float* ws  = (float*)d_ws;                      // ~343 KB used
    float* out = (float*)d_out;

    // init min arrays to 0x7F7F7F7F (= 3.39e38 > any clamped distance),
    // accumulators + arrival counter to 0
    hipMemsetAsync(ws, 0x7F, (size_t)WS_ACC * sizeof(float), stream);
    hipMemsetAsync(ws + WS_ACC, 0, 21 * sizeof(float), stream);
    k1_main  <<<NB_K1, 256, 0, stream>>>(pc_gt, pc_pred, fff, ws);
    k2_reduce<<<NB_K2, 256, 0, stream>>>(fff, A_gt, ws, out);
}